// Round 8
// baseline (98.382 us; speedup 1.0000x reference)
//
#include <hip/hip_runtime.h>
#include <math.h>

#define T_FRAMES 1025
#define TSTRIDE  1032          // row stride for Ht; 1032*8 = 129*64 -> rows 64B-aligned
#define BATCH    4
#define LWAV     131072
#define KWC      1023
#define MFFT     2048
#define PI_F     3.14159265358979323846f

struct c32 { float r, i; };
__device__ __forceinline__ c32 mkc(float r, float i){ c32 z; z.r=r; z.i=i; return z; }
__device__ __forceinline__ c32 cadd(c32 a, c32 b){ return mkc(a.r+b.r, a.i+b.i); }
__device__ __forceinline__ c32 csub(c32 a, c32 b){ return mkc(a.r-b.r, a.i-b.i); }
__device__ __forceinline__ c32 cmul(c32 a, c32 b){ return mkc(a.r*b.r - a.i*b.i, a.r*b.i + a.i*b.r); }
__device__ __forceinline__ c32 cni(c32 a){ return mkc(a.i, -a.r); }           // a * (-i)
#define C8F 0.70710678118654752440f
__device__ __forceinline__ c32 c8p(c32 a){ return mkc(C8F*(a.r+a.i), C8F*(a.i-a.r)); }   // * e^{-i pi/4}
__device__ __forceinline__ c32 c8m(c32 a){ return mkc(C8F*(a.i-a.r), -C8F*(a.r+a.i)); }  // * e^{-i 3pi/4}

__device__ __forceinline__ int pX(int j){ return j + (j >> 5); }
__device__ __forceinline__ int pS(int j){ return j + (j >> 3); }
__device__ __forceinline__ int rev9(int j){ return (int)(__brev((unsigned)j) >> 23); }

// e^{-2*pi*i*r/2048} via fast HW sincos
__device__ __forceinline__ c32 wexp(int r) {
    float s, c;
    __sincosf((float)r * (-PI_F / 1024.0f), &s, &c);
    return mkc(c, s);
}

// ---- radix-8 DIF step; w3 = W^{pos*2^(stages-3 of this level)}
__device__ __forceinline__ void dif8_tw(c32 y[8], c32 w3) {
    c32 w2 = cmul(w3, w3), w1 = cmul(w2, w2);
    c32 u[8], v[8], d;
    d = csub(y[0], y[4]); u[0] = cadd(y[0], y[4]); u[4] = cmul(d, w3);
    d = csub(y[1], y[5]); u[1] = cadd(y[1], y[5]); u[5] = c8p(cmul(d, w3));
    d = csub(y[2], y[6]); u[2] = cadd(y[2], y[6]); u[6] = cni(cmul(d, w3));
    d = csub(y[3], y[7]); u[3] = cadd(y[3], y[7]); u[7] = c8m(cmul(d, w3));
    d = csub(u[0], u[2]); v[0] = cadd(u[0], u[2]); v[2] = cmul(d, w2);
    d = csub(u[1], u[3]); v[1] = cadd(u[1], u[3]); v[3] = cni(cmul(d, w2));
    d = csub(u[4], u[6]); v[4] = cadd(u[4], u[6]); v[6] = cmul(d, w2);
    d = csub(u[5], u[7]); v[5] = cadd(u[5], u[7]); v[7] = cni(cmul(d, w2));
    d = csub(v[0], v[1]); y[0] = cadd(v[0], v[1]); y[1] = cmul(d, w1);
    d = csub(v[2], v[3]); y[2] = cadd(v[2], v[3]); y[3] = cmul(d, w1);
    d = csub(v[4], v[5]); y[4] = cadd(v[4], v[5]); y[5] = cmul(d, w1);
    d = csub(v[6], v[7]); y[6] = cadd(v[6], v[7]); y[7] = cmul(d, w1);
}
__device__ __forceinline__ void dif8_nt(c32 y[8]) {
    c32 u[8], v[8], d;
    d = csub(y[0], y[4]); u[0] = cadd(y[0], y[4]); u[4] = d;
    d = csub(y[1], y[5]); u[1] = cadd(y[1], y[5]); u[5] = c8p(d);
    d = csub(y[2], y[6]); u[2] = cadd(y[2], y[6]); u[6] = cni(d);
    d = csub(y[3], y[7]); u[3] = cadd(y[3], y[7]); u[7] = c8m(d);
    d = csub(u[0], u[2]); v[0] = cadd(u[0], u[2]); v[2] = d;
    d = csub(u[1], u[3]); v[1] = cadd(u[1], u[3]); v[3] = cni(d);
    d = csub(u[4], u[6]); v[4] = cadd(u[4], u[6]); v[6] = d;
    d = csub(u[5], u[7]); v[5] = cadd(u[5], u[7]); v[7] = cni(d);
    d = csub(v[0], v[1]); y[0] = cadd(v[0], v[1]); y[1] = d;
    d = csub(v[2], v[3]); y[2] = cadd(v[2], v[3]); y[3] = d;
    d = csub(v[4], v[5]); y[4] = cadd(v[4], v[5]); y[5] = d;
    d = csub(v[6], v[7]); y[6] = cadd(v[6], v[7]); y[7] = d;
}
__device__ __forceinline__ void dit8_tw(c32 y[8], c32 w3) {
    c32 w2 = cmul(w3, w3), w1 = cmul(w2, w2);
    c32 u[8], v[8], t;
    t = cmul(y[1], w1); u[0] = cadd(y[0], t); u[1] = csub(y[0], t);
    t = cmul(y[3], w1); u[2] = cadd(y[2], t); u[3] = csub(y[2], t);
    t = cmul(y[5], w1); u[4] = cadd(y[4], t); u[5] = csub(y[4], t);
    t = cmul(y[7], w1); u[6] = cadd(y[6], t); u[7] = csub(y[6], t);
    t = cmul(u[2], w2);      v[0] = cadd(u[0], t); v[2] = csub(u[0], t);
    t = cni(cmul(u[3], w2)); v[1] = cadd(u[1], t); v[3] = csub(u[1], t);
    t = cmul(u[6], w2);      v[4] = cadd(u[4], t); v[6] = csub(u[4], t);
    t = cni(cmul(u[7], w2)); v[5] = cadd(u[5], t); v[7] = csub(u[5], t);
    t = cmul(v[4], w3);      y[0] = cadd(v[0], t); y[4] = csub(v[0], t);
    t = c8p(cmul(v[5], w3)); y[1] = cadd(v[1], t); y[5] = csub(v[1], t);
    t = cni(cmul(v[6], w3)); y[2] = cadd(v[2], t); y[6] = csub(v[2], t);
    t = c8m(cmul(v[7], w3)); y[3] = cadd(v[3], t); y[7] = csub(v[3], t);
}
__device__ __forceinline__ void dit8_nt(c32 y[8]) {
    c32 u[8], v[8], t;
    u[0] = cadd(y[0], y[1]); u[1] = csub(y[0], y[1]);
    u[2] = cadd(y[2], y[3]); u[3] = csub(y[2], y[3]);
    u[4] = cadd(y[4], y[5]); u[5] = csub(y[4], y[5]);
    u[6] = cadd(y[6], y[7]); u[7] = csub(y[6], y[7]);
    t = u[2];      v[0] = cadd(u[0], t); v[2] = csub(u[0], t);
    t = cni(u[3]); v[1] = cadd(u[1], t); v[3] = csub(u[1], t);
    t = u[6];      v[4] = cadd(u[4], t); v[6] = csub(u[4], t);
    t = cni(u[7]); v[5] = cadd(u[5], t); v[7] = csub(u[5], t);
    t = v[4];      y[0] = cadd(v[0], t); y[4] = csub(v[0], t);
    t = c8p(v[5]); y[1] = cadd(v[1], t); y[5] = csub(v[1], t);
    t = cni(v[6]); y[2] = cadd(v[2], t); y[6] = csub(v[2], t);
    t = c8m(v[7]); y[3] = cadd(v[3], t); y[7] = csub(v[3], t);
}
__device__ __forceinline__ void dif4(c32 y[4]) {
    c32 u0 = cadd(y[0], y[2]), d0 = csub(y[0], y[2]);
    c32 u1 = cadd(y[1], y[3]), d1 = cni(csub(y[1], y[3]));
    y[0] = cadd(u0, u1); y[1] = csub(u0, u1);
    y[2] = cadd(d0, d1); y[3] = csub(d0, d1);
}
__device__ __forceinline__ void dit4(c32 y[4], c32 w) {
    c32 w2 = cmul(w, w);
    c32 t1 = cmul(y[1], w2); c32 u0 = cadd(y[0], t1), u1 = csub(y[0], t1);
    c32 t3 = cmul(y[3], w2); c32 u2 = cadd(y[2], t3), u3 = csub(y[2], t3);
    c32 s2 = cmul(u2, w);      y[0] = cadd(u0, s2); y[2] = csub(u0, s2);
    c32 s3 = cni(cmul(u3, w)); y[1] = cadd(u1, s3); y[3] = csub(u1, s3);
}

// ---------------- stage1: blocks 0..515 = STFT (real-pair packed); 516..522 = alpha-FFT.
__global__ __launch_bounds__(256) void stage1_kernel(const float* __restrict__ wave,
                                                     const float* __restrict__ win,
                                                     const float* __restrict__ ar,
                                                     const float* __restrict__ ai,
                                                     float2* __restrict__ Ht,
                                                     float2* __restrict__ Afbr) {
    __shared__ float lds[4608];      // stft: Fr[4][576] | Fi[4][576]; afft: Xr[2112] | Xi[2112]
    const int tid = threadIdx.x;

    if (blockIdx.x < 516) {
        // ---- STFT: wave w packs frames (t0+2w, t0+2w+1) as re+i*im into ONE 512-pt FFT
        const int w = tid >> 6, l = tid & 63;
        const int b = blockIdx.x / 129;
        const int t0 = (blockIdx.x - b * 129) << 3;
        const float* wb = wave + (size_t)b * LWAV;
        float* Fr = lds + w * 576;
        float* Fi = lds + 2304 + w * 576;
        const int te = t0 + (w << 1);          // even frame of this wave's pair

        if (te < T_FRAMES) {
            c32 y[8];
#pragma unroll
            for (int k = 0; k < 8; ++k) {
                int s = l + (k << 6);
                float wv = win[s];
                int pe = te * 128 + s - 256;
                int ixe = pe < 0 ? -pe : (pe >= LWAV ? 2 * LWAV - 2 - pe : pe);
                float xr = wb[ixe] * wv;
                float xi = 0.f;
                if (te + 1 < T_FRAMES) {
                    int po = pe + 128;
                    int ixo = po < 0 ? -po : (po >= LWAV ? 2 * LWAV - 2 - po : po);
                    xi = wb[ixo] * wv;
                }
                y[k] = mkc(xr, xi);
            }
            // phase A (9,8,7): w3 = e^{-2pi i l/512}
            dif8_tw(y, wexp(l << 2));
#pragma unroll
            for (int k = 0; k < 8; ++k) { int p = pS(l + (k << 6)); Fr[p] = y[k].r; Fi[p] = y[k].i; }
            __builtin_amdgcn_wave_barrier();
            // phase B (6,5,4)
            {
                int base = ((l >> 3) << 6) + (l & 7);
#pragma unroll
                for (int k = 0; k < 8; ++k) { int p = pS(base + (k << 3)); y[k] = mkc(Fr[p], Fi[p]); }
                dif8_tw(y, wexp((l & 7) << 5));
#pragma unroll
                for (int k = 0; k < 8; ++k) { int p = pS(base + (k << 3)); Fr[p] = y[k].r; Fi[p] = y[k].i; }
            }
            __builtin_amdgcn_wave_barrier();
            // phase C (3,2,1)
            {
#pragma unroll
                for (int k = 0; k < 8; ++k) { int p = pS((l << 3) + k); y[k] = mkc(Fr[p], Fi[p]); }
                dif8_nt(y);
#pragma unroll
                for (int k = 0; k < 8; ++k) { int p = pS((l << 3) + k); Fr[p] = y[k].r; Fi[p] = y[k].i; }
            }
        }
        __syncthreads();
        // writeout + untangle: rows p = tid, tid+256 with bin = rev9(p) <= 256.
        // H_even[bin] = (Z[bin]+conj(Z[512-bin]))/2 ; H_odd = (Z[bin]-conj(Z[512-bin]))/(2i)
        const bool full = (t0 + 7 < T_FRAMES);
#pragma unroll
        for (int h = 0; h < 2; ++h) {
            int p = tid + (h << 8);
            int bin = rev9(p);
            if (bin > 256) continue;
            int pm = rev9((512 - bin) & 511);
            int ps1 = pS(p), ps2 = pS(pm);
            size_t rowbase = (size_t)(b * 512 + p) * TSTRIDE + t0;
            if (full) {
                float4* dst = (float4*)(Ht + rowbase);
#pragma unroll
                for (int j = 0; j < 4; ++j) {
                    float z1r = lds[j*576 + ps1], z1i = lds[2304 + j*576 + ps1];
                    float z2r = lds[j*576 + ps2], z2i = lds[2304 + j*576 + ps2];
                    float er = 0.5f * (z1r + z2r), ei = 0.5f * (z1i - z2i);
                    float orr = 0.5f * (z1i + z2i), oi = 0.5f * (z2r - z1r);
                    dst[j] = make_float4(er, ei, orr, oi);
                }
            } else {
                for (int jj = 0; jj < 8; ++jj) {
                    if (t0 + jj >= T_FRAMES) break;
                    int j = jj >> 1;
                    float z1r = lds[j*576 + ps1], z1i = lds[2304 + j*576 + ps1];
                    float z2r = lds[j*576 + ps2], z2i = lds[2304 + j*576 + ps2];
                    float2 hv = (jj & 1)
                        ? make_float2(0.5f * (z1i + z2i), 0.5f * (z2r - z1r))
                        : make_float2(0.5f * (z1r + z2r), 0.5f * (z1i - z2i));
                    Ht[rowbase + jj] = hv;
                }
            }
        }
    } else {
        // ---- alpha FFT: Af_br[q][p] = conj(DIF2048(conj(alpha_q) zero-pad))[p]
        float* Xr = lds;
        float* Xi = lds + 2112;
        const int q = blockIdx.x - 516;
        c32 y[8];
#pragma unroll
        for (int k = 0; k < 8; ++k) {
            int j = tid + (k << 8);
            y[k] = (j < KWC) ? mkc(ar[q * KWC + j], -ai[q * KWC + j]) : mkc(0.f, 0.f);
        }
        // A (11,10,9)
        dif8_tw(y, wexp(tid));
#pragma unroll
        for (int k = 0; k < 8; ++k) { int p = pX(tid + (k << 8)); Xr[p] = y[k].r; Xi[p] = y[k].i; }
        __syncthreads();
        // B (8,7,6)
        {
            int base = ((tid >> 5) << 8) + (tid & 31);
#pragma unroll
            for (int k = 0; k < 8; ++k) { int p = pX(base + (k << 5)); y[k] = mkc(Xr[p], Xi[p]); }
            dif8_tw(y, wexp((tid & 31) << 3));
#pragma unroll
            for (int k = 0; k < 8; ++k) { int p = pX(base + (k << 5)); Xr[p] = y[k].r; Xi[p] = y[k].i; }
        }
        __syncthreads();
        // C (5,4,3)
        {
            int base = ((tid & 63) << 5) + (tid >> 6);
#pragma unroll
            for (int k = 0; k < 8; ++k) { int p = pX(base + (k << 2)); y[k] = mkc(Xr[p], Xi[p]); }
            dif8_tw(y, wexp((tid >> 6) << 6));
#pragma unroll
            for (int k = 0; k < 8; ++k) { int p = pX(base + (k << 2)); Xr[p] = y[k].r; Xi[p] = y[k].i; }
        }
        __syncthreads();
        // D (2,1) radix-4, write conj
#pragma unroll
        for (int h = 0; h < 2; ++h) {
            int g = tid + (h << 8);
            c32 z4[4];
#pragma unroll
            for (int k = 0; k < 4; ++k) { int p = pX((g << 2) + k); z4[k] = mkc(Xr[p], Xi[p]); }
            dif4(z4);
#pragma unroll
            for (int k = 0; k < 4; ++k) Afbr[(q << 11) + (g << 2) + k] = make_float2(z4[k].r, -z4[k].i);
        }
    }
}

// ---------------- conv: n = 0..256 only; rows 1..255 weighted x2 (mirror symmetry).
__global__ __launch_bounds__(256) void conv_fft_kernel(const float2* __restrict__ Ht,
                                                       const float2* __restrict__ Afbr,
                                                       float* __restrict__ out) {
    __shared__ float Xr[2112], Xi[2112];
    __shared__ float red[4];
    const int tid = threadIdx.x;
    const int b = blockIdx.x / 257;
    const int n = blockIdx.x - b * 257;                // bin 0..256
    const int pr = rev9(n);                            // row holding bin n

    const float2* row = Ht + (size_t)(b * 512 + pr) * TSTRIDE;
    c32 y[8];
#pragma unroll
    for (int k = 0; k < 8; ++k) {
        int j = tid + (k << 8);
        c32 v = mkc(0.f, 0.f);
        if (j < T_FRAMES) { float2 h = row[j]; v = mkc(h.x, h.y); }
        y[k] = v;
    }
    // DIF A (11,10,9)
    dif8_tw(y, wexp(tid));
#pragma unroll
    for (int k = 0; k < 8; ++k) { int p = pX(tid + (k << 8)); Xr[p] = y[k].r; Xi[p] = y[k].i; }
    __syncthreads();
    // DIF B (8,7,6)
    {
        int base = ((tid >> 5) << 8) + (tid & 31);
#pragma unroll
        for (int k = 0; k < 8; ++k) { int p = pX(base + (k << 5)); y[k] = mkc(Xr[p], Xi[p]); }
        dif8_tw(y, wexp((tid & 31) << 3));
#pragma unroll
        for (int k = 0; k < 8; ++k) { int p = pX(base + (k << 5)); Xr[p] = y[k].r; Xi[p] = y[k].i; }
    }
    __syncthreads();
    // DIF C (5,4,3)
    {
        int base = ((tid & 63) << 5) + (tid >> 6);
#pragma unroll
        for (int k = 0; k < 8; ++k) { int p = pX(base + (k << 2)); y[k] = mkc(Xr[p], Xi[p]); }
        dif8_tw(y, wexp((tid >> 6) << 6));
#pragma unroll
        for (int k = 0; k < 8; ++k) { int p = pX(base + (k << 2)); Xr[p] = y[k].r; Xi[p] = y[k].i; }
    }
    __syncthreads();
    // FUSED: DIF D (radix-4 x2) + pointwise + DIT A (1,2,3)
    {
        c32 p1 = wexp(-(n << 2));                      // e^{+2pi i n/512}
        c32 p2 = cmul(p1, p1);
        c32 p3 = cmul(p2, p1);
        const int a0 = tid << 3;
        const int p0 = pX(a0);
        c32 z[8];
#pragma unroll
        for (int k = 0; k < 8; ++k) z[k] = mkc(Xr[p0 + k], Xi[p0 + k]);
        dif4(&z[0]);
        dif4(&z[4]);
        const float4* af4 = (const float4*)(Afbr + a0);
#pragma unroll
        for (int k = 0; k < 8; ++k) {
            float4 a;
            c32 Kk;
            a = af4[(3 << 10) + (k >> 1)];     // q'=0
            float ax = (k & 1) ? a.z : a.x, ay = (k & 1) ? a.w : a.y;
            Kk = mkc(ax, ay);
            a = af4[(4 << 10) + (k >> 1)]; ax = (k & 1) ? a.z : a.x; ay = (k & 1) ? a.w : a.y;
            Kk.r += p1.r * ax - p1.i * ay;  Kk.i += p1.r * ay + p1.i * ax;
            a = af4[(2 << 10) + (k >> 1)]; ax = (k & 1) ? a.z : a.x; ay = (k & 1) ? a.w : a.y;
            Kk.r += p1.r * ax + p1.i * ay;  Kk.i += p1.r * ay - p1.i * ax;
            a = af4[(5 << 10) + (k >> 1)]; ax = (k & 1) ? a.z : a.x; ay = (k & 1) ? a.w : a.y;
            Kk.r += p2.r * ax - p2.i * ay;  Kk.i += p2.r * ay + p2.i * ax;
            a = af4[(1 << 10) + (k >> 1)]; ax = (k & 1) ? a.z : a.x; ay = (k & 1) ? a.w : a.y;
            Kk.r += p2.r * ax + p2.i * ay;  Kk.i += p2.r * ay - p2.i * ax;
            a = af4[(6 << 10) + (k >> 1)]; ax = (k & 1) ? a.z : a.x; ay = (k & 1) ? a.w : a.y;
            Kk.r += p3.r * ax - p3.i * ay;  Kk.i += p3.r * ay + p3.i * ax;
            a = af4[(0 << 10) + (k >> 1)]; ax = (k & 1) ? a.z : a.x; ay = (k & 1) ? a.w : a.y;
            Kk.r += p3.r * ax + p3.i * ay;  Kk.i += p3.r * ay - p3.i * ax;
            c32 P = cmul(z[k], Kk);
            z[k] = mkc(P.r, -P.i);             // conj for inverse-via-forward
        }
        dit8_nt(z);
#pragma unroll
        for (int k = 0; k < 8; ++k) { Xr[p0 + k] = z[k].r; Xi[p0 + k] = z[k].i; }
    }
    __syncthreads();
    // DIT B (4,5,6)
    {
        int G = (((tid & 63) >> 3) << 2) + (tid >> 6);
        int pos = tid & 7;
        int base = (G << 6) + pos;
#pragma unroll
        for (int k = 0; k < 8; ++k) { int p = pX(base + (k << 3)); y[k] = mkc(Xr[p], Xi[p]); }
        dit8_tw(y, wexp(pos << 5));
#pragma unroll
        for (int k = 0; k < 8; ++k) { int p = pX(base + (k << 3)); Xr[p] = y[k].r; Xi[p] = y[k].i; }
    }
    __syncthreads();
    // DIT C (7,8,9)
    {
        int base = ((tid >> 6) << 9) + (tid & 63);
#pragma unroll
        for (int k = 0; k < 8; ++k) { int p = pX(base + (k << 6)); y[k] = mkc(Xr[p], Xi[p]); }
        dit8_tw(y, wexp((tid & 63) << 2));
#pragma unroll
        for (int k = 0; k < 8; ++k) { int p = pX(base + (k << 6)); Xr[p] = y[k].r; Xi[p] = y[k].i; }
    }
    __syncthreads();
    // DIT D (10,11) radix-4 + masked |.|^2
    float local = 0.f;
#pragma unroll
    for (int h = 0; h < 2; ++h) {
        int pos = tid + (h << 8);
        c32 z4[4];
#pragma unroll
        for (int k = 0; k < 4; ++k) { int p = pX(pos + (k << 9)); z4[k] = mkc(Xr[p], Xi[p]); }
        dit4(z4, wexp(pos));
        local += z4[0].r * z4[0].r + z4[0].i * z4[0].i;                 // s = pos < 514 always
        if (pos < 2)  local += z4[1].r * z4[1].r + z4[1].i * z4[1].i;   // s in {512,513}
        if (pos >= 1) local += z4[3].r * z4[3].r + z4[3].i * z4[3].i;   // s >= 1537
    }
    local *= (n == 0 || n == 256) ? 1.0f : 2.0f;       // mirror-row weight
#pragma unroll
    for (int off = 32; off >= 1; off >>= 1) local += __shfl_down(local, off);
    if ((tid & 63) == 0) red[tid >> 6] = local;
    __syncthreads();
    if (tid == 0) {
        const float SCALE =
            (float)(1.0 / ((double)MFFT * (double)MFFT * (double)BATCH * (double)T_FRAMES));
        atomicAdd(out, (red[0] + red[1] + red[2] + red[3]) * SCALE);
    }
}

extern "C" void kernel_launch(void* const* d_in, const int* in_sizes, int n_in,
                              void* d_out, int out_size, void* d_ws, size_t ws_size,
                              hipStream_t stream) {
    (void)in_sizes; (void)n_in; (void)out_size; (void)ws_size;
    const float* wave   = (const float*)d_in[0];
    const float* window = (const float*)d_in[1];
    const float* ar     = (const float*)d_in[2];
    const float* ai     = (const float*)d_in[3];
    float* out = (float*)d_out;

    char* ws = (char*)d_ws;
    float2* Ht   = (float2*)ws;                          // 4*512*1032*8 = 16,908,288 B
    float2* Afbr = (float2*)(ws + 16908288);             // 7*2048*8    =    114,688 B

    hipMemsetAsync(out, 0, sizeof(float), stream);
    stage1_kernel<<<523, 256, 0, stream>>>(wave, window, ar, ai, Ht, Afbr);
    conv_fft_kernel<<<BATCH * 257, 256, 0, stream>>>(Ht, Afbr, out);
}